// Round 2
// baseline (3442.097 us; speedup 1.0000x reference)
//
#include <hip/hip_runtime.h>
#include <hip/hip_bf16.h>

// GumbelDecoderEncoder: B=16384, E=256, V=128, T=16, TAU=1.
// Key facts exploited:
//  * y is numerically EXACTLY one-hot (straight-through) or zero (dead rows),
//    so input-side matmuls are table lookups: Gi[v] = Wih@(Wd2e[:,v]+bd2e)+bih,
//    row 129 (v==V) = zero-token case (emb = bd2e only).
//  * argmax(softmax((l+g)/tau)) == argmax(l+g)  (tau=1>0, softmax monotone).
//  * Encoder sieve (u_t[:,0]>0.5) can never fire: decoder zeroes y the step
//    token 0 appears. reconst = final encoder state.
//  * Everything is row-independent: each wave owns 8 rows for all 16 steps,
//    hidden states live in wave-private LDS. No cross-wave/block deps.
// R1 fix: d_out is FLOAT32 (reference outputs f32/int32/f32 -> "else float*").
// R0's bf16 writes put N=16 (0x4180) into the high half of f32 word
// 16,777,216 -> the observed chunk-0 absmax of exactly 16.0.

namespace {
constexpr int kB  = 16384;
constexpr int kE  = 256;
constexpr int kV  = 128;
constexpr int kT  = 16;
constexpr int kG3 = 768;

constexpr int kOffWdhhT  = 0;                       // [256][768]
constexpr int kOffWehhT  = kG3 * kE;                // [256][768]
constexpr int kOffWe2dT  = 2 * kG3 * kE;            // [256][128]
constexpr int kOffDecTab = kOffWe2dT + kV * kE;     // [129][768]
constexpr int kOffEncTab = kOffDecTab + 129 * kG3;  // [129][768]
// total ws use: 624128 floats = 2.44 MB
}

__device__ __forceinline__ float sigmf(float v) { return 1.0f / (1.0f + expf(-v)); }
__device__ __forceinline__ float gumbelf(float u) {
  return -logf(-logf(u + 1e-10f) + 1e-10f);
}

// ---- prepass 1: k-major transposes of Whh (dec/enc) and We2d ----
__global__ void prep_transpose(const float* __restrict__ dWhh,
                               const float* __restrict__ eWhh,
                               const float* __restrict__ We2d,
                               float* __restrict__ ws) {
  const int n1 = kG3 * kE;
  const int n2 = n1 + kG3 * kE;
  const int n3 = n2 + kV * kE;
  for (int i = blockIdx.x * blockDim.x + threadIdx.x; i < n3;
       i += gridDim.x * blockDim.x) {
    if (i < n1) {
      const int k = i / kG3, j = i - k * kG3;
      ws[i] = dWhh[j * kE + k];
    } else if (i < n2) {
      const int t = i - n1;
      const int k = t / kG3, j = t - k * kG3;
      ws[i] = eWhh[j * kE + k];
    } else {
      const int t = i - n2;
      const int k = t / kV, v = t - k * kV;
      ws[i] = We2d[v * kE + k];
    }
  }
}

// ---- prepass 2: token->gi tables (v==128 is the zero-token row) ----
__global__ void prep_tables(const float* __restrict__ Wih,
                            const float* __restrict__ Wd2e,
                            const float* __restrict__ bd2e,
                            const float* __restrict__ bih,
                            float* __restrict__ tab) {
  const int i = blockIdx.x * blockDim.x + threadIdx.x;
  if (i >= 129 * kG3) return;
  const int v = i / kG3, j = i - v * kG3;
  const float* wr = Wih + j * kE;
  float acc = 0.0f;
  if (v < kV) {
    for (int k = 0; k < kE; ++k) acc = fmaf(wr[k], Wd2e[k * kV + v] + bd2e[k], acc);
  } else {
    for (int k = 0; k < kE; ++k) acc = fmaf(wr[k], bd2e[k], acc);
  }
  tab[i] = acc + bih[j];
}

// gh = h @ Whh^T for this wave's 8 rows; thread covers units e0..e0+3 of all
// three gates (j = gate*256 + e). acc[row][gate][cc].
__device__ __forceinline__ void gru_half(float acc[8][3][4],
                                         const float (*__restrict__ h)[8],
                                         const float* __restrict__ WT,
                                         const int e0) {
#pragma unroll
  for (int r = 0; r < 8; ++r)
#pragma unroll
    for (int g = 0; g < 3; ++g)
#pragma unroll
      for (int c = 0; c < 4; ++c) acc[r][g][c] = 0.0f;
#pragma unroll 2
  for (int k = 0; k < kE; ++k) {
    const float4 hA = *(const float4*)(&h[k][0]);   // broadcast LDS reads
    const float4 hB = *(const float4*)(&h[k][4]);
    const float* wp = WT + k * kG3 + e0;            // coalesced dwordx4 streams
    const float4 w0 = *(const float4*)(wp);
    const float4 w1 = *(const float4*)(wp + 256);
    const float4 w2 = *(const float4*)(wp + 512);
    const float hv[8] = {hA.x, hA.y, hA.z, hA.w, hB.x, hB.y, hB.z, hB.w};
    const float wv[3][4] = {{w0.x, w0.y, w0.z, w0.w},
                            {w1.x, w1.y, w1.z, w1.w},
                            {w2.x, w2.y, w2.z, w2.w}};
#pragma unroll
    for (int r = 0; r < 8; ++r)
#pragma unroll
      for (int g = 0; g < 3; ++g)
#pragma unroll
        for (int c = 0; c < 4; ++c)
          acc[r][g][c] = fmaf(hv[r], wv[g][c], acc[r][g][c]);
  }
}

// GRU pointwise: r=sig(ir+hr), z=sig(iz+hz), n=tanh(in + r*hn), h'=(1-z)n+zh.
// hr/hz/hn include bhh; ir/iz/in come from the token table.
__device__ __forceinline__ void gru_pointwise(float acc[8][3][4],
                                              float (*__restrict__ h)[8],
                                              const float* __restrict__ Tab,
                                              const int tok[8],
                                              const float4& br4, const float4& bz4,
                                              const float4& bn4, const int e0) {
  const float br[4] = {br4.x, br4.y, br4.z, br4.w};
  const float bz[4] = {bz4.x, bz4.y, bz4.z, bz4.w};
  const float bn[4] = {bn4.x, bn4.y, bn4.z, bn4.w};
#pragma unroll
  for (int r = 0; r < 8; ++r) {
    const float* gp = Tab + tok[r] * kG3 + e0;  // tok wave-uniform -> coalesced
    const float4 g0 = *(const float4*)(gp);
    const float4 g1 = *(const float4*)(gp + 256);
    const float4 g2 = *(const float4*)(gp + 512);
    const float gi[3][4] = {{g0.x, g0.y, g0.z, g0.w},
                            {g1.x, g1.y, g1.z, g1.w},
                            {g2.x, g2.y, g2.z, g2.w}};
#pragma unroll
    for (int c = 0; c < 4; ++c) {
      const float rg = sigmf(gi[0][c] + acc[r][0][c] + br[c]);
      const float zg = sigmf(gi[1][c] + acc[r][1][c] + bz[c]);
      const float ng = tanhf(gi[2][c] + rg * (acc[r][2][c] + bn[c]));
      acc[r][0][c] = ng;  // stash n
      acc[r][1][c] = zg;  // stash z
    }
  }
#pragma unroll
  for (int c = 0; c < 4; ++c) {
    const int e = e0 + c;
    const float4 hA = *(const float4*)(&h[e][0]);
    const float4 hB = *(const float4*)(&h[e][4]);
    const float ho[8] = {hA.x, hA.y, hA.z, hA.w, hB.x, hB.y, hB.z, hB.w};
    float hn[8];
#pragma unroll
    for (int r = 0; r < 8; ++r)
      hn[r] = (1.0f - acc[r][1][c]) * acc[r][0][c] + acc[r][1][c] * ho[r];
    *(float4*)(&h[e][0]) = make_float4(hn[0], hn[1], hn[2], hn[3]);
    *(float4*)(&h[e][4]) = make_float4(hn[4], hn[5], hn[6], hn[7]);
  }
}

__launch_bounds__(256, 2)
__global__ void gumbel_fused(const float* __restrict__ x,
                             const float* __restrict__ unoise,
                             const float* __restrict__ dbhh,
                             const float* __restrict__ dbe2d,
                             const float* __restrict__ ebhh,
                             const float* __restrict__ ws,
                             float* __restrict__ out) {
  const float* WdhhT  = ws + kOffWdhhT;
  const float* WehhT  = ws + kOffWehhT;
  const float* We2dT  = ws + kOffWe2dT;
  const float* DecTab = ws + kOffDecTab;
  const float* EncTab = ws + kOffEncTab;

  __shared__ float hbuf[2][4][kE][8];  // [dec/enc][wave][k][row] 64 KB

  const int tid  = (int)threadIdx.x;
  const int w    = tid >> 6;
  const int jx   = tid & 63;
  const int row0 = (int)blockIdx.x * 32 + w * 8;  // 8 rows per wave
  const int e0   = jx * 4;

  float (*hd)[8] = hbuf[0][w];
  float (*he)[8] = hbuf[1][w];

  // init: hdec = x (coalesced global reads), henc = 0
  for (int i = jx; i < kE * 8; i += 64) {
    const int r = i >> 8, k = i & (kE - 1);
    hd[k][r] = x[(size_t)(row0 + r) * kE + k];
    he[k][r] = 0.0f;
  }
  __syncthreads();

  int tok[8], Nn[8];
  bool alive[8];
#pragma unroll
  for (int r = 0; r < 8; ++r) { tok[r] = kV; Nn[r] = kT; alive[r] = true; }

  const float4 dbr = *(const float4*)(dbhh + e0);
  const float4 dbz = *(const float4*)(dbhh + 256 + e0);
  const float4 dbn = *(const float4*)(dbhh + 512 + e0);
  const float4 ebr = *(const float4*)(ebhh + e0);
  const float4 ebz = *(const float4*)(ebhh + 256 + e0);
  const float4 ebn = *(const float4*)(ebhh + 512 + e0);
  const float2 be2 = *(const float2*)(dbe2d + 2 * jx);

  float acc[8][3][4];

  for (int t = 0; t < kT; ++t) {
    // ---- decoder GRU (uses tok from previous step) ----
    gru_half(acc, hd, WdhhT, e0);
    gru_pointwise(acc, hd, DecTab, tok, dbr, dbz, dbn, e0);
    __syncthreads();  // lockstep (LDS is wave-private; barrier keeps L1 reuse)

    // ---- logits + gumbel + argmax; lane covers cols 2jx, 2jx+1 ----
    float l0[8], l1[8];
#pragma unroll
    for (int r = 0; r < 8; ++r) { l0[r] = 0.0f; l1[r] = 0.0f; }
#pragma unroll 2
    for (int k = 0; k < kE; ++k) {
      const float4 hA = *(const float4*)(&hd[k][0]);
      const float4 hB = *(const float4*)(&hd[k][4]);
      const float2 wv = *(const float2*)(We2dT + k * kV + 2 * jx);
      const float hv[8] = {hA.x, hA.y, hA.z, hA.w, hB.x, hB.y, hB.z, hB.w};
#pragma unroll
      for (int r = 0; r < 8; ++r) {
        l0[r] = fmaf(hv[r], wv.x, l0[r]);
        l1[r] = fmaf(hv[r], wv.y, l1[r]);
      }
    }
    const float* up = unoise + ((size_t)t * kB + row0) * kV + 2 * jx;
#pragma unroll
    for (int r = 0; r < 8; ++r) {
      const float2 u = *(const float2*)(up + (size_t)r * kV);
      const float a0 = l0[r] + be2.x + gumbelf(u.x);
      const float a1 = l1[r] + be2.y + gumbelf(u.y);
      float mv; int mi;
      if (a1 > a0) { mv = a1; mi = 2 * jx + 1; } else { mv = a0; mi = 2 * jx; }
      // first-occurrence argmax across 64 lanes (max, min-index-on-tie)
#pragma unroll
      for (int off = 32; off >= 1; off >>= 1) {
        const float ov = __shfl_xor(mv, off, 64);
        const int   oi = __shfl_xor(mi, off, 64);
        if (ov > mv || (ov == mv && oi < mi)) { mv = ov; mi = oi; }
      }
      const bool ended = (mi == 0);
      if (ended) Nn[r] = (Nn[r] < t) ? Nn[r] : t;
      const bool anew = alive[r] && !ended;
      alive[r] = anew;
      tok[r] = anew ? mi : kV;  // kV == zero-token marker
      float2 pr;
      pr.x = (anew && mi == 2 * jx) ? 1.0f : 0.0f;
      pr.y = (anew && mi == 2 * jx + 1) ? 1.0f : 0.0f;
      *reinterpret_cast<float2*>(
          out + ((size_t)(row0 + r) * kT + t) * kV + 2 * jx) = pr;
    }

    // ---- encoder GRU (uses tok emitted this step) ----
    gru_half(acc, he, WehhT, e0);
    gru_pointwise(acc, he, EncTab, tok, ebr, ebz, ebn, e0);
    __syncthreads();
  }

  // ---- outputs: N then reconst (= final encoder state; sieve never fires) ----
  const size_t uttN = (size_t)kB * kT * kV;
#pragma unroll
  for (int r = 0; r < 8; ++r)
    if (jx == r) out[uttN + row0 + r] = (float)Nn[r];
  for (int i = jx; i < kE * 8; i += 64) {
    const int r = i >> 8, k = i & (kE - 1);
    out[uttN + kB + (size_t)(row0 + r) * kE + k] = he[k][r];
  }
}

extern "C" void kernel_launch(void* const* d_in, const int* in_sizes, int n_in,
                              void* d_out, int out_size, void* d_ws, size_t ws_size,
                              hipStream_t stream) {
  (void)in_sizes; (void)n_in; (void)out_size; (void)ws_size;
  const float* x      = (const float*)d_in[0];
  // d_in[1] = global_idxes (unused by reference)
  const float* unoise = (const float*)d_in[2];
  const float* dWd2e  = (const float*)d_in[3];
  const float* dbd2e  = (const float*)d_in[4];
  const float* dWih   = (const float*)d_in[5];
  const float* dWhh   = (const float*)d_in[6];
  const float* dbih   = (const float*)d_in[7];
  const float* dbhh   = (const float*)d_in[8];
  const float* dWe2d  = (const float*)d_in[9];
  const float* dbe2d  = (const float*)d_in[10];
  const float* eWd2e  = (const float*)d_in[11];
  const float* ebd2e  = (const float*)d_in[12];
  const float* eWih   = (const float*)d_in[13];
  const float* eWhh   = (const float*)d_in[14];
  const float* ebih   = (const float*)d_in[15];
  const float* ebhh   = (const float*)d_in[16];
  float* ws = (float*)d_ws;  // needs 624128 floats (2.44 MB)

  prep_transpose<<<1664, 256, 0, stream>>>(dWhh, eWhh, dWe2d, ws);
  prep_tables<<<(129 * kG3 + 255) / 256, 256, 0, stream>>>(
      dWih, dWd2e, dbd2e, dbih, ws + kOffDecTab);
  prep_tables<<<(129 * kG3 + 255) / 256, 256, 0, stream>>>(
      eWih, eWd2e, ebd2e, ebih, ws + kOffEncTab);
  gumbel_fused<<<kB / 32, 256, 0, stream>>>(
      x, unoise, dbhh, dbe2d, ebhh, ws, (float*)d_out);
}